// Round 1
// baseline (628.242 us; speedup 1.0000x reference)
//
#include <hip/hip_runtime.h>
#include <hip/hip_bf16.h>
#include <stdint.h>

typedef unsigned short u16;
typedef unsigned int u32;
typedef float f32x4 __attribute__((ext_vector_type(4)));
typedef short bf16x8 __attribute__((ext_vector_type(8)));

#define DEV static __device__ __forceinline__

DEV u16 f2bf(float x) {
    u32 u = __float_as_uint(x);
    u32 r = (u + 0x7fffu + ((u >> 16) & 1u)) >> 16;   // RNE (no NaN inputs expected)
    return (u16)r;
}
DEV float bf2f(u16 u) { return __uint_as_float(((u32)u) << 16); }

// ---------------------------------------------------------------------------
// Pack kernels
// ---------------------------------------------------------------------------

// fp32 -> bf16, 8 elements/thread, fully coalesced
__global__ __launch_bounds__(256) void k_cvt_bf16(const float* __restrict__ in,
                                                  u16* __restrict__ out, int n8) {
    int i = blockIdx.x * 256 + threadIdx.x;
    if (i >= n8) return;
    const float4* p = (const float4*)in + (size_t)i * 2;
    float4 a = p[0], b = p[1];
    u16 r[8];
    r[0] = f2bf(a.x); r[1] = f2bf(a.y); r[2] = f2bf(a.z); r[3] = f2bf(a.w);
    r[4] = f2bf(b.x); r[5] = f2bf(b.y); r[6] = f2bf(b.z); r[7] = f2bf(b.w);
    *(uint4*)(out + (size_t)i * 8) = *(const uint4*)r;
}

// in [K][N] fp32  ->  out [N][K] bf16 ; 32x32 LDS-tiled transpose (both sides coalesced)
__global__ __launch_bounds__(256) void k_transpose_cvt(const float* __restrict__ in,
                                                       u16* __restrict__ out,
                                                       int K, int N) {
    __shared__ float tile[32][33];   // +1 pad: conflict-free transpose read
    int tiles_n = N >> 5;
    int tk = blockIdx.x / tiles_n, tn = blockIdx.x % tiles_n;
    int tx = threadIdx.x & 31, ty = threadIdx.x >> 5;   // ty in 0..7
    int k0 = tk * 32, n0 = tn * 32;
#pragma unroll
    for (int i = 0; i < 4; ++i)
        tile[ty * 4 + i][tx] = in[(size_t)(k0 + ty * 4 + i) * N + n0 + tx];
    __syncthreads();
#pragma unroll
    for (int i = 0; i < 4; ++i)
        out[(size_t)(n0 + ty * 4 + i) * K + k0 + tx] = f2bf(tile[tx][ty * 4 + i]);
}

// Wc [1024][11] + Wr [1024][5] -> Whead [1024][16] fp32
__global__ __launch_bounds__(256) void k_pack_head(const float* __restrict__ Wc,
                                                   const float* __restrict__ Wr,
                                                   float* __restrict__ Whead) {
    int r = blockIdx.x * 256 + threadIdx.x;
    if (r >= 1024) return;
    float* o = Whead + (size_t)r * 16;
#pragma unroll
    for (int c = 0; c < 11; ++c) o[c] = Wc[(size_t)r * 11 + c];
#pragma unroll
    for (int c = 0; c < 5; ++c) o[11 + c] = Wr[(size_t)r * 5 + c];
}

// ---------------------------------------------------------------------------
// bf16 GEMM, C = relu(A @ B^T + bias), bf16 out.
// A [M][K] bf16 row-major, Bt [N][K] bf16 row-major. BM=128 BN=64 BK=64,
// 256 threads (4 waves, 2x2), each wave 64x32 out, 16x16x32 MFMA,
// global_load_lds dwordx4 staging (m97 structure).
// ---------------------------------------------------------------------------
__global__ __launch_bounds__(256) void k_gemm_bias_relu(
    const u16* __restrict__ A, const u16* __restrict__ Bt,
    const float* __restrict__ bias, u16* __restrict__ C,
    int M, int N, int K) {
    __shared__ u16 As[128 * 64];   // 16 KiB
    __shared__ u16 Bs[64 * 64];    //  8 KiB

    // bijective XCD swizzle (gridDim.x % 8 == 0 here: 512)
    int nwg = gridDim.x;
    int cpx = nwg >> 3;
    int bid = blockIdx.x;
    int swz = (bid & 7) * cpx + (bid >> 3);
    int ntn = N >> 6;                 // tiles along N (BN=64)
    int bm = swz / ntn, bn = swz % ntn;

    int tid = threadIdx.x;
    int lane = tid & 63, wid = tid >> 6;
    int wm = wid >> 1, wn = wid & 1;  // 2x2 wave grid
    const int tm0 = bm * 128, tn0 = bn * 64;

    const int l8 = lane >> 3, l7 = lane & 7;

    f32x4 acc[4][2] = {};

    int kt = K >> 6;
    for (int t = 0; t < kt; ++t) {
        int k0 = t << 6;
        // stage A tile: 16 segs x 1024B; wave wid owns segs wid*4 .. +3
#pragma unroll
        for (int i = 0; i < 4; ++i) {
            int seg = wid * 4 + i;
            const u16* g = A + (size_t)(tm0 + seg * 8 + l8) * K + k0 + l7 * 8;
            __builtin_amdgcn_global_load_lds(
                (const __attribute__((address_space(1))) u32*)g,
                (__attribute__((address_space(3))) u32*)&As[seg * 512], 16, 0, 0);
        }
        // stage B tile: 8 segs; wave wid owns segs wid*2 .. +1
#pragma unroll
        for (int i = 0; i < 2; ++i) {
            int seg = wid * 2 + i;
            const u16* g = Bt + (size_t)(tn0 + seg * 8 + l8) * K + k0 + l7 * 8;
            __builtin_amdgcn_global_load_lds(
                (const __attribute__((address_space(1))) u32*)g,
                (__attribute__((address_space(3))) u32*)&Bs[seg * 512], 16, 0, 0);
        }
        __syncthreads();   // drains vmcnt(0): LDS tiles ready

#pragma unroll
        for (int kk = 0; kk < 2; ++kk) {
            int kc = kk * 32 + (lane >> 4) * 8;
            bf16x8 a[4], b[2];
#pragma unroll
            for (int m = 0; m < 4; ++m)
                a[m] = *(const bf16x8*)&As[(wm * 64 + m * 16 + (lane & 15)) * 64 + kc];
#pragma unroll
            for (int n = 0; n < 2; ++n)
                b[n] = *(const bf16x8*)&Bs[(wn * 32 + n * 16 + (lane & 15)) * 64 + kc];
#pragma unroll
            for (int m = 0; m < 4; ++m)
#pragma unroll
                for (int n = 0; n < 2; ++n)
                    acc[m][n] = __builtin_amdgcn_mfma_f32_16x16x32_bf16(
                        a[m], b[n], acc[m][n], 0, 0, 0);
        }
        __syncthreads();
    }

    // epilogue: bias + relu + bf16 store. C/D layout: col=lane&15, row=(lane>>4)*4+r
    int cr = lane >> 4, cc = lane & 15;
#pragma unroll
    for (int n = 0; n < 2; ++n) {
        int col = tn0 + wn * 32 + n * 16 + cc;
        float bv = bias[col];
#pragma unroll
        for (int m = 0; m < 4; ++m) {
            int row0 = tm0 + wm * 64 + m * 16 + cr * 4;
#pragma unroll
            for (int r = 0; r < 4; ++r) {
                float v = fmaxf(acc[m][n][r] + bv, 0.0f);
                C[(size_t)(row0 + r) * N + col] = f2bf(v);
            }
        }
    }
}

// ---------------------------------------------------------------------------
// Heads: one wave per row. 16 outputs (11 cls + 5 reg), then box decode.
// ---------------------------------------------------------------------------
__global__ __launch_bounds__(256) void k_head(
    const u16* __restrict__ h2, const float* __restrict__ Whead,
    const float* __restrict__ bc, const float* __restrict__ br,
    const float* __restrict__ boxes, const float* __restrict__ strides,
    float* __restrict__ cls_out, float* __restrict__ dec_out,
    float* __restrict__ rois_out) {
    int lane = threadIdx.x & 63;
    int row = blockIdx.x * 4 + (threadIdx.x >> 6);

    const u16* hr = h2 + (size_t)row * 1024;
    float acc[16];
#pragma unroll
    for (int i = 0; i < 16; ++i) acc[i] = 0.0f;

#pragma unroll
    for (int j = 0; j < 16; ++j) {
        int k = j * 64 + lane;                     // coalesced across wave
        float h = bf2f(hr[k]);
        const float4* wp = (const float4*)(Whead + (size_t)k * 16);
        float4 q0 = wp[0], q1 = wp[1], q2 = wp[2], q3 = wp[3];
        acc[0]  = fmaf(h, q0.x, acc[0]);  acc[1]  = fmaf(h, q0.y, acc[1]);
        acc[2]  = fmaf(h, q0.z, acc[2]);  acc[3]  = fmaf(h, q0.w, acc[3]);
        acc[4]  = fmaf(h, q1.x, acc[4]);  acc[5]  = fmaf(h, q1.y, acc[5]);
        acc[6]  = fmaf(h, q1.z, acc[6]);  acc[7]  = fmaf(h, q1.w, acc[7]);
        acc[8]  = fmaf(h, q2.x, acc[8]);  acc[9]  = fmaf(h, q2.y, acc[9]);
        acc[10] = fmaf(h, q2.z, acc[10]); acc[11] = fmaf(h, q2.w, acc[11]);
        acc[12] = fmaf(h, q3.x, acc[12]); acc[13] = fmaf(h, q3.y, acc[13]);
        acc[14] = fmaf(h, q3.z, acc[14]); acc[15] = fmaf(h, q3.w, acc[15]);
    }
    // butterfly reduce across the 64-lane wave
#pragma unroll
    for (int i = 0; i < 16; ++i) {
#pragma unroll
        for (int off = 32; off > 0; off >>= 1)
            acc[i] += __shfl_xor(acc[i], off);
    }

    if (lane == 0) {
        float* co = cls_out + (size_t)row * 11;
#pragma unroll
        for (int c = 0; c < 11; ++c) co[c] = acc[c] + bc[c];

        const float STD[5] = {0.1f, 0.1f, 0.2f, 0.2f, 0.1f};
        float reg[5];
#pragma unroll
        for (int j = 0; j < 5; ++j) reg[j] = (acc[11 + j] + br[j]) * STD[j];

        const float* bx = boxes + (size_t)row * 5;
        const float* st = strides + (size_t)row * 5;
        float b0 = bx[0], b1 = bx[1], b2 = bx[2], b3 = bx[3], b4 = bx[4];
        float s0 = st[0], s1 = st[1], s2 = st[2], s3 = st[3];

        float dx = b2 * reg[0] + b0;
        float dy = b3 * reg[1] + b1;
        float dw = b2 * expf(reg[2]);
        float dh = b3 * expf(reg[3]);
        float da = b4 * expf(reg[4]);

        float* dd = dec_out + (size_t)row * 5;
        dd[0] = dx * s0; dd[1] = dy * s1; dd[2] = dw * s2; dd[3] = dh * s3; dd[4] = da;

        float* rr = rois_out + (size_t)row * 5;
        rr[0] = b0 * s0; rr[1] = b1 * s1; rr[2] = b2 * s2; rr[3] = b3 * s3; rr[4] = b4;
    }
}

// ---------------------------------------------------------------------------
// launch
// ---------------------------------------------------------------------------
extern "C" void kernel_launch(void* const* d_in, const int* in_sizes, int n_in,
                              void* d_out, int out_size, void* d_ws, size_t ws_size,
                              hipStream_t stream) {
    const float* features = (const float*)d_in[0];
    const float* boxes    = (const float*)d_in[1];
    const float* strides  = (const float*)d_in[2];
    const float* W1 = (const float*)d_in[3];
    const float* b1 = (const float*)d_in[4];
    const float* W2 = (const float*)d_in[5];
    const float* b2 = (const float*)d_in[6];
    const float* Wc = (const float*)d_in[7];
    const float* bc = (const float*)d_in[8];
    const float* Wr = (const float*)d_in[9];
    const float* br = (const float*)d_in[10];

    // problem constants
    const int M = 4096;      // B*N = 2*2048
    const int K = 12544;     // 256*7*7
    const int H = 1024;

    // workspace layout (bytes)
    char* ws = (char*)d_ws;
    u16*   Abf   = (u16*)(ws + 0);            // 4096*12544 bf16 = 102,760,448 B
    u16*   W1T   = (u16*)(ws + 102760448);    // 1024*12544 bf16 =  25,690,112 B
    u16*   W2T   = (u16*)(ws + 128450560);    // 1024*1024  bf16 =   2,097,152 B
    float* Whead = (float*)(ws + 130547712);  // 1024*16 f32     =      65,536 B
    u16*   h1    = (u16*)(ws + 130613248);    // 4096*1024 bf16  =   8,388,608 B
    u16*   h2    = (u16*)(ws + 139001856);    // 4096*1024 bf16  =   8,388,608 B
    // total: 147,390,464 B

    // 1) pack: features -> bf16 (51,380,224 elems / 8 per thread)
    k_cvt_bf16<<<25088, 256, 0, stream>>>(features, Abf, 6422528);
    // 2) W1 [K][H] -> W1T [H][K] bf16 ; W2 [H][H] -> W2T
    k_transpose_cvt<<<(K / 32) * (H / 32), 256, 0, stream>>>(W1, W1T, K, H);
    k_transpose_cvt<<<(H / 32) * (H / 32), 256, 0, stream>>>(W2, W2T, H, H);
    // 3) head weights
    k_pack_head<<<4, 256, 0, stream>>>(Wc, Wr, Whead);

    // 4) GEMM1: h1 = relu(Abf @ W1T^T + b1)   [4096 x 1024], K=12544
    k_gemm_bias_relu<<<(M / 128) * (H / 64), 256, 0, stream>>>(Abf, W1T, b1, h1, M, H, K);
    // 5) GEMM2: h2 = relu(h1 @ W2T^T + b2)    [4096 x 1024], K=1024
    k_gemm_bias_relu<<<(M / 128) * (H / 64), 256, 0, stream>>>(h1, W2T, b2, h2, M, H, H);

    // 6) heads + decode
    float* cls  = (float*)d_out;                   // 4096*11
    float* dec  = cls + (size_t)4096 * 11;         // 4096*5
    float* rois = dec + (size_t)4096 * 5;          // 4096*5
    k_head<<<1024, 256, 0, stream>>>(h2, Whead, bc, br, boxes, strides, cls, dec, rois);
}

// Round 2
// 616.198 us; speedup vs baseline: 1.0195x; 1.0195x over previous
//
#include <hip/hip_runtime.h>
#include <hip/hip_bf16.h>
#include <stdint.h>

typedef unsigned short u16;
typedef unsigned int u32;
typedef float f32x4 __attribute__((ext_vector_type(4)));
typedef short bf16x8 __attribute__((ext_vector_type(8)));

#define DEV static __device__ __forceinline__

DEV u16 f2bf(float x) {
    u32 u = __float_as_uint(x);
    u32 r = (u + 0x7fffu + ((u >> 16) & 1u)) >> 16;   // RNE
    return (u16)r;
}
DEV float bf2f(u16 u) { return __uint_as_float(((u32)u) << 16); }
// HW packed cvt (RNE), dst.lo = bf16(lo), dst.hi = bf16(hi)
DEV u32 pk2bf(float lo, float hi) {
    u32 r;
    asm("v_cvt_pk_bf16_f32 %0, %1, %2" : "=v"(r) : "v"(lo), "v"(hi));
    return r;
}

// ---------------------------------------------------------------------------
// Pack kernels
// ---------------------------------------------------------------------------

// in [K][N] fp32  ->  out [N][K] bf16 ; 32x32 LDS-tiled transpose
__global__ __launch_bounds__(256) void k_transpose_cvt(const float* __restrict__ in,
                                                       u16* __restrict__ out,
                                                       int K, int N) {
    __shared__ float tile[32][33];
    int tiles_n = N >> 5;
    int tk = blockIdx.x / tiles_n, tn = blockIdx.x % tiles_n;
    int tx = threadIdx.x & 31, ty = threadIdx.x >> 5;
    int k0 = tk * 32, n0 = tn * 32;
#pragma unroll
    for (int i = 0; i < 4; ++i)
        tile[ty * 4 + i][tx] = in[(size_t)(k0 + ty * 4 + i) * N + n0 + tx];
    __syncthreads();
#pragma unroll
    for (int i = 0; i < 4; ++i)
        out[(size_t)(n0 + ty * 4 + i) * K + k0 + tx] = f2bf(tile[tx][ty * 4 + i]);
}

// Wc [1024][11] + Wr [1024][5] -> Whead [1024][16] fp32
__global__ __launch_bounds__(256) void k_pack_head(const float* __restrict__ Wc,
                                                   const float* __restrict__ Wr,
                                                   float* __restrict__ Whead) {
    int r = blockIdx.x * 256 + threadIdx.x;
    if (r >= 1024) return;
    float* o = Whead + (size_t)r * 16;
#pragma unroll
    for (int c = 0; c < 11; ++c) o[c] = Wc[(size_t)r * 11 + c];
#pragma unroll
    for (int c = 0; c < 5; ++c) o[11 + c] = Wr[(size_t)r * 5 + c];
}

// ---------------------------------------------------------------------------
// GEMM1 (split-K=2): P[s] = A(fp32, cvt in staging) @ Bt^T, fp32 partials.
// BM=128 BN=64 BK=64, 256 thr (2x2 waves, wave 64x32), 16x16x32 MFMA.
// LDS tiles XOR-swizzled: byte ^= (row&7)<<4 (T2).
// ---------------------------------------------------------------------------
__global__ __launch_bounds__(256, 4) void k_gemm1(
    const float* __restrict__ A, const u16* __restrict__ Bt,
    float* __restrict__ P, int M, int N, int K, int KHALF) {
    __shared__ u16 As[128 * 64];   // 16 KiB, row stride 128 B
    __shared__ u16 Bs[64 * 64];    //  8 KiB

    int nwg = gridDim.x;              // 1024
    int cpx = nwg >> 3;
    int bid = blockIdx.x;
    int swz = (bid & 7) * cpx + (bid >> 3);
    int split = swz >> 9;             // 0..1
    int tile = swz & 511;
    int bm = tile >> 4, bn = tile & 15;

    int tid = threadIdx.x;
    int lane = tid & 63, wid = tid >> 6;
    int wm = wid >> 1, wn = wid & 1;
    const int tm0 = bm * 128, tn0 = bn * 64;
    const int kbeg = split * KHALF;

    const int l8 = lane >> 3, l7 = lane & 7;
    const int bsrc = ((l7 ^ l8) << 3);   // inverse-swizzled source col (elems)

    f32x4 acc[4][2] = {};

    int kt = KHALF >> 6;
    for (int t = 0; t < kt; ++t) {
        int k0 = kbeg + (t << 6);
        // ---- B stage: gload_lds (linear dest) from pre-swizzled source
#pragma unroll
        for (int i = 0; i < 2; ++i) {
            int seg = wid * 2 + i;
            const u16* g = Bt + (size_t)(tn0 + seg * 8 + l8) * K + k0 + bsrc;
            __builtin_amdgcn_global_load_lds(
                (const __attribute__((address_space(1))) u32*)g,
                (__attribute__((address_space(3))) u32*)&Bs[seg * 512], 16, 0, 0);
        }
        // ---- A stage: fp32 load -> cvt_pk bf16 -> swizzled ds_write
#pragma unroll
        for (int h = 0; h < 2; ++h) {
            float4 fa[2][2];
#pragma unroll
            for (int i = 0; i < 2; ++i) {
                int s = (h * 2 + i) * 256 + tid;
                int r = s >> 3, cg = s & 7;
                const float* g = A + (size_t)(tm0 + r) * K + k0 + cg * 8;
                fa[i][0] = *(const float4*)g;
                fa[i][1] = *(const float4*)(g + 4);
            }
#pragma unroll
            for (int i = 0; i < 2; ++i) {
                int s = (h * 2 + i) * 256 + tid;
                int r = s >> 3, cg = s & 7;
                u32 pk[4];
                pk[0] = pk2bf(fa[i][0].x, fa[i][0].y);
                pk[1] = pk2bf(fa[i][0].z, fa[i][0].w);
                pk[2] = pk2bf(fa[i][1].x, fa[i][1].y);
                pk[3] = pk2bf(fa[i][1].z, fa[i][1].w);
                int cb = (cg << 4) ^ ((r & 7) << 4);
                *(uint4*)((char*)As + r * 128 + cb) = *(const uint4*)pk;
            }
        }
        __syncthreads();

#pragma unroll
        for (int kk = 0; kk < 2; ++kk) {
            int cb = (kk << 6) + ((lane >> 4) << 4);
            bf16x8 a[4], b[2];
#pragma unroll
            for (int m = 0; m < 4; ++m) {
                int r = wm * 64 + m * 16 + (lane & 15);
                a[m] = *(const bf16x8*)((const char*)As + r * 128 + (cb ^ ((r & 7) << 4)));
            }
#pragma unroll
            for (int n = 0; n < 2; ++n) {
                int r = wn * 32 + n * 16 + (lane & 15);
                b[n] = *(const bf16x8*)((const char*)Bs + r * 128 + (cb ^ ((r & 7) << 4)));
            }
#pragma unroll
            for (int m = 0; m < 4; ++m)
#pragma unroll
                for (int n = 0; n < 2; ++n)
                    acc[m][n] = __builtin_amdgcn_mfma_f32_16x16x32_bf16(
                        a[m], b[n], acc[m][n], 0, 0, 0);
        }
        __syncthreads();
    }

    float* Ps = P + (size_t)split * M * N;
    int cr = lane >> 4, cc = lane & 15;
#pragma unroll
    for (int n = 0; n < 2; ++n) {
        int col = tn0 + wn * 32 + n * 16 + cc;
#pragma unroll
        for (int m = 0; m < 4; ++m) {
            int row0 = tm0 + wm * 64 + m * 16 + cr * 4;
#pragma unroll
            for (int r = 0; r < 4; ++r)
                Ps[(size_t)(row0 + r) * N + col] = acc[m][n][r];
        }
    }
}

// combine: h1 = bf16(relu(P0 + P1 + bias)), 8 elems/thread
__global__ __launch_bounds__(256) void k_combine(const float* __restrict__ P,
                                                 const float* __restrict__ bias,
                                                 u16* __restrict__ out,
                                                 int MN, int N) {
    int i = blockIdx.x * 256 + threadIdx.x;
    int ncol8 = N >> 3;
    int row = i / ncol8, c8 = i - row * ncol8;
    size_t off = (size_t)row * N + (size_t)c8 * 8;
    const float4* p0 = (const float4*)(P + off);
    const float4* p1 = (const float4*)(P + (size_t)MN + off);
    const float4* bp = (const float4*)(bias + (size_t)c8 * 8);
    float4 a0 = p0[0], a1 = p0[1];
    float4 b0 = p1[0], b1 = p1[1];
    float4 q0 = bp[0], q1 = bp[1];
    float v0 = fmaxf(a0.x + b0.x + q0.x, 0.f), v1 = fmaxf(a0.y + b0.y + q0.y, 0.f);
    float v2 = fmaxf(a0.z + b0.z + q0.z, 0.f), v3 = fmaxf(a0.w + b0.w + q0.w, 0.f);
    float v4 = fmaxf(a1.x + b1.x + q1.x, 0.f), v5 = fmaxf(a1.y + b1.y + q1.y, 0.f);
    float v6 = fmaxf(a1.z + b1.z + q1.z, 0.f), v7 = fmaxf(a1.w + b1.w + q1.w, 0.f);
    u32 pk[4] = {pk2bf(v0, v1), pk2bf(v2, v3), pk2bf(v4, v5), pk2bf(v6, v7)};
    *(uint4*)(out + off) = *(const uint4*)pk;
}

// ---------------------------------------------------------------------------
// GEMM2: C = relu(A @ Bt^T + bias) bf16, A bf16 via gload_lds (pre-swizzled src)
// ---------------------------------------------------------------------------
__global__ __launch_bounds__(256) void k_gemm2(
    const u16* __restrict__ A, const u16* __restrict__ Bt,
    const float* __restrict__ bias, u16* __restrict__ C,
    int M, int N, int K) {
    __shared__ u16 As[128 * 64];
    __shared__ u16 Bs[64 * 64];

    int nwg = gridDim.x;            // 512
    int cpx = nwg >> 3;
    int bid = blockIdx.x;
    int swz = (bid & 7) * cpx + (bid >> 3);
    int ntn = N >> 6;
    int bm = swz / ntn, bn = swz % ntn;

    int tid = threadIdx.x;
    int lane = tid & 63, wid = tid >> 6;
    int wm = wid >> 1, wn = wid & 1;
    const int tm0 = bm * 128, tn0 = bn * 64;

    const int l8 = lane >> 3, l7 = lane & 7;
    const int bsrc = ((l7 ^ l8) << 3);

    f32x4 acc[4][2] = {};

    int kt = K >> 6;
    for (int t = 0; t < kt; ++t) {
        int k0 = t << 6;
#pragma unroll
        for (int i = 0; i < 4; ++i) {
            int seg = wid * 4 + i;
            const u16* g = A + (size_t)(tm0 + seg * 8 + l8) * K + k0 + bsrc;
            __builtin_amdgcn_global_load_lds(
                (const __attribute__((address_space(1))) u32*)g,
                (__attribute__((address_space(3))) u32*)&As[seg * 512], 16, 0, 0);
        }
#pragma unroll
        for (int i = 0; i < 2; ++i) {
            int seg = wid * 2 + i;
            const u16* g = Bt + (size_t)(tn0 + seg * 8 + l8) * K + k0 + bsrc;
            __builtin_amdgcn_global_load_lds(
                (const __attribute__((address_space(1))) u32*)g,
                (__attribute__((address_space(3))) u32*)&Bs[seg * 512], 16, 0, 0);
        }
        __syncthreads();

#pragma unroll
        for (int kk = 0; kk < 2; ++kk) {
            int cb = (kk << 6) + ((lane >> 4) << 4);
            bf16x8 a[4], b[2];
#pragma unroll
            for (int m = 0; m < 4; ++m) {
                int r = wm * 64 + m * 16 + (lane & 15);
                a[m] = *(const bf16x8*)((const char*)As + r * 128 + (cb ^ ((r & 7) << 4)));
            }
#pragma unroll
            for (int n = 0; n < 2; ++n) {
                int r = wn * 32 + n * 16 + (lane & 15);
                b[n] = *(const bf16x8*)((const char*)Bs + r * 128 + (cb ^ ((r & 7) << 4)));
            }
#pragma unroll
            for (int m = 0; m < 4; ++m)
#pragma unroll
                for (int n = 0; n < 2; ++n)
                    acc[m][n] = __builtin_amdgcn_mfma_f32_16x16x32_bf16(
                        a[m], b[n], acc[m][n], 0, 0, 0);
        }
        __syncthreads();
    }

    int cr = lane >> 4, cc = lane & 15;
#pragma unroll
    for (int n = 0; n < 2; ++n) {
        int col = tn0 + wn * 32 + n * 16 + cc;
        float bv = bias[col];
#pragma unroll
        for (int m = 0; m < 4; ++m) {
            int row0 = tm0 + wm * 64 + m * 16 + cr * 4;
#pragma unroll
            for (int r = 0; r < 4; ++r) {
                float v = fmaxf(acc[m][n][r] + bv, 0.0f);
                C[(size_t)(row0 + r) * N + col] = f2bf(v);
            }
        }
    }
}

// ---------------------------------------------------------------------------
// Heads: one wave per row; 16 outputs (11 cls + 5 reg) + box decode
// ---------------------------------------------------------------------------
__global__ __launch_bounds__(256) void k_head(
    const u16* __restrict__ h2, const float* __restrict__ Whead,
    const float* __restrict__ bc, const float* __restrict__ br,
    const float* __restrict__ boxes, const float* __restrict__ strides,
    float* __restrict__ cls_out, float* __restrict__ dec_out,
    float* __restrict__ rois_out) {
    int lane = threadIdx.x & 63;
    int row = blockIdx.x * 4 + (threadIdx.x >> 6);

    const u16* hr = h2 + (size_t)row * 1024;
    float acc[16];
#pragma unroll
    for (int i = 0; i < 16; ++i) acc[i] = 0.0f;

#pragma unroll
    for (int j = 0; j < 16; ++j) {
        int k = j * 64 + lane;
        float h = bf2f(hr[k]);
        const float4* wp = (const float4*)(Whead + (size_t)k * 16);
        float4 q0 = wp[0], q1 = wp[1], q2 = wp[2], q3 = wp[3];
        acc[0]  = fmaf(h, q0.x, acc[0]);  acc[1]  = fmaf(h, q0.y, acc[1]);
        acc[2]  = fmaf(h, q0.z, acc[2]);  acc[3]  = fmaf(h, q0.w, acc[3]);
        acc[4]  = fmaf(h, q1.x, acc[4]);  acc[5]  = fmaf(h, q1.y, acc[5]);
        acc[6]  = fmaf(h, q1.z, acc[6]);  acc[7]  = fmaf(h, q1.w, acc[7]);
        acc[8]  = fmaf(h, q2.x, acc[8]);  acc[9]  = fmaf(h, q2.y, acc[9]);
        acc[10] = fmaf(h, q2.z, acc[10]); acc[11] = fmaf(h, q2.w, acc[11]);
        acc[12] = fmaf(h, q3.x, acc[12]); acc[13] = fmaf(h, q3.y, acc[13]);
        acc[14] = fmaf(h, q3.z, acc[14]); acc[15] = fmaf(h, q3.w, acc[15]);
    }
#pragma unroll
    for (int i = 0; i < 16; ++i) {
#pragma unroll
        for (int off = 32; off > 0; off >>= 1)
            acc[i] += __shfl_xor(acc[i], off);
    }

    if (lane == 0) {
        float* co = cls_out + (size_t)row * 11;
#pragma unroll
        for (int c = 0; c < 11; ++c) co[c] = acc[c] + bc[c];

        const float STD[5] = {0.1f, 0.1f, 0.2f, 0.2f, 0.1f};
        float reg[5];
#pragma unroll
        for (int j = 0; j < 5; ++j) reg[j] = (acc[11 + j] + br[j]) * STD[j];

        const float* bx = boxes + (size_t)row * 5;
        const float* st = strides + (size_t)row * 5;
        float b0 = bx[0], b1 = bx[1], b2 = bx[2], b3 = bx[3], b4 = bx[4];
        float s0 = st[0], s1 = st[1], s2 = st[2], s3 = st[3];

        float dx = b2 * reg[0] + b0;
        float dy = b3 * reg[1] + b1;
        float dw = b2 * expf(reg[2]);
        float dh = b3 * expf(reg[3]);
        float da = b4 * expf(reg[4]);

        float* dd = dec_out + (size_t)row * 5;
        dd[0] = dx * s0; dd[1] = dy * s1; dd[2] = dw * s2; dd[3] = dh * s3; dd[4] = da;

        float* rr = rois_out + (size_t)row * 5;
        rr[0] = b0 * s0; rr[1] = b1 * s1; rr[2] = b2 * s2; rr[3] = b3 * s3; rr[4] = b4;
    }
}

// ---------------------------------------------------------------------------
// launch
// ---------------------------------------------------------------------------
extern "C" void kernel_launch(void* const* d_in, const int* in_sizes, int n_in,
                              void* d_out, int out_size, void* d_ws, size_t ws_size,
                              hipStream_t stream) {
    const float* features = (const float*)d_in[0];
    const float* boxes    = (const float*)d_in[1];
    const float* strides  = (const float*)d_in[2];
    const float* W1 = (const float*)d_in[3];
    const float* b1 = (const float*)d_in[4];
    const float* W2 = (const float*)d_in[5];
    const float* b2 = (const float*)d_in[6];
    const float* Wc = (const float*)d_in[7];
    const float* bc = (const float*)d_in[8];
    const float* Wr = (const float*)d_in[9];
    const float* br = (const float*)d_in[10];

    const int M = 4096;      // B*N
    const int K = 12544;     // 256*7*7
    const int H = 1024;

    // workspace layout (bytes)
    char* ws = (char*)d_ws;
    u16*   W1T   = (u16*)(ws + 0);            // 25,690,112 B
    u16*   W2T   = (u16*)(ws + 25690112);     //  2,097,152 B
    float* Whead = (float*)(ws + 27787264);   //     65,536 B
    float* P     = (float*)(ws + 27852800);   // 33,554,432 B (2 x 16 MB fp32)
    u16*   h1    = (u16*)(ws + 61407232);     //  8,388,608 B
    u16*   h2    = (u16*)(ws + 69795840);     //  8,388,608 B
    // total 78,184,448 B

    // weights pack
    k_transpose_cvt<<<(K / 32) * (H / 32), 256, 0, stream>>>(W1, W1T, K, H);
    k_transpose_cvt<<<(H / 32) * (H / 32), 256, 0, stream>>>(W2, W2T, H, H);
    k_pack_head<<<4, 256, 0, stream>>>(Wc, Wr, Whead);

    // GEMM1 split-K=2: P[s] = features @ W1T^T (fp32 partials)
    k_gemm1<<<1024, 256, 0, stream>>>(features, W1T, P, M, H, K, K / 2);
    // h1 = relu(P0 + P1 + b1) in bf16
    k_combine<<<(M * H / 8) / 256, 256, 0, stream>>>(P, b1, h1, M * H, H);
    // GEMM2: h2 = relu(h1 @ W2T^T + b2)
    k_gemm2<<<(M / 128) * (H / 64), 256, 0, stream>>>(h1, W2T, b2, h2, M, H, H);

    // heads + decode
    float* cls  = (float*)d_out;               // 4096*11
    float* dec  = cls + (size_t)4096 * 11;     // 4096*5
    float* rois = dec + (size_t)4096 * 5;      // 4096*5
    k_head<<<1024, 256, 0, stream>>>(h2, Whead, bc, br, boxes, strides, cls, dec, rois);
}

// Round 3
// 595.684 us; speedup vs baseline: 1.0547x; 1.0344x over previous
//
#include <hip/hip_runtime.h>
#include <hip/hip_bf16.h>
#include <stdint.h>

typedef unsigned short u16;
typedef unsigned int u32;
typedef float f32x4 __attribute__((ext_vector_type(4)));
typedef short bf16x8 __attribute__((ext_vector_type(8)));

#define DEV static __device__ __forceinline__

DEV u16 f2bf(float x) {
    u32 u = __float_as_uint(x);
    u32 r = (u + 0x7fffu + ((u >> 16) & 1u)) >> 16;   // RNE
    return (u16)r;
}
DEV float bf2f(u16 u) { return __uint_as_float(((u32)u) << 16); }
DEV u32 pk2bf(float lo, float hi) {
    u32 r;
    asm("v_cvt_pk_bf16_f32 %0, %1, %2" : "=v"(r) : "v"(lo), "v"(hi));
    return r;
}

// ---------------------------------------------------------------------------
// Pack kernels
// ---------------------------------------------------------------------------

// fp32 -> bf16, 8 elems/thread, coalesced
__global__ __launch_bounds__(256) void k_cvt_bf16(const float* __restrict__ in,
                                                  u16* __restrict__ out, int n8) {
    int i = blockIdx.x * 256 + threadIdx.x;
    if (i >= n8) return;
    const float4* p = (const float4*)in + (size_t)i * 2;
    float4 a = p[0], b = p[1];
    u32 pk[4] = {pk2bf(a.x, a.y), pk2bf(a.z, a.w), pk2bf(b.x, b.y), pk2bf(b.z, b.w)};
    *(uint4*)(out + (size_t)i * 8) = *(const uint4*)pk;
}

// in [K][N] fp32 -> out [N][K] bf16 ; 32x32 LDS-tiled transpose
__global__ __launch_bounds__(256) void k_transpose_cvt(const float* __restrict__ in,
                                                       u16* __restrict__ out,
                                                       int K, int N) {
    __shared__ float tile[32][33];
    int tiles_n = N >> 5;
    int tk = blockIdx.x / tiles_n, tn = blockIdx.x % tiles_n;
    int tx = threadIdx.x & 31, ty = threadIdx.x >> 5;
    int k0 = tk * 32, n0 = tn * 32;
#pragma unroll
    for (int i = 0; i < 4; ++i)
        tile[ty * 4 + i][tx] = in[(size_t)(k0 + ty * 4 + i) * N + n0 + tx];
    __syncthreads();
#pragma unroll
    for (int i = 0; i < 4; ++i)
        out[(size_t)(n0 + ty * 4 + i) * K + k0 + tx] = f2bf(tile[tx][ty * 4 + i]);
}

// Wc [1024][11] + Wr [1024][5] -> Whead [1024][16] fp32
__global__ __launch_bounds__(256) void k_pack_head(const float* __restrict__ Wc,
                                                   const float* __restrict__ Wr,
                                                   float* __restrict__ Whead) {
    int r = blockIdx.x * 256 + threadIdx.x;
    if (r >= 1024) return;
    float* o = Whead + (size_t)r * 16;
#pragma unroll
    for (int c = 0; c < 11; ++c) o[c] = Wc[(size_t)r * 11 + c];
#pragma unroll
    for (int c = 0; c < 5; ++c) o[11 + c] = Wr[(size_t)r * 5 + c];
}

// ---------------------------------------------------------------------------
// bf16 GEMM, C = relu(A @ Bt^T + bias) in bf16.
// BM=128 BN=64 BK=64, 256 thr (2x2 waves, wave 64x32), 16x16x32 MFMA.
// 2-phase double-buffered global_load_lds prefetch (T3-minimum):
//   STAGE(nxt) ; compute(cur) ; __syncthreads (vmcnt+lgkm drain) ; swap.
// T2 XOR swizzle byte ^= (row&7)<<4, applied as inverse-swizzled global
// source + swizzled ds_read (rule #21: gload_lds dest stays linear).
// ---------------------------------------------------------------------------
__global__ __launch_bounds__(256, 2) void k_gemm_bias_relu(
    const u16* __restrict__ A, const u16* __restrict__ Bt,
    const float* __restrict__ bias, u16* __restrict__ C,
    int M, int N, int K) {
    __shared__ u16 As[2][128 * 64];   // 2 x 16 KiB
    __shared__ u16 Bs[2][64 * 64];    // 2 x  8 KiB

    int nwg = gridDim.x;              // 512 (multiple of 8)
    int cpx = nwg >> 3;
    int bid = blockIdx.x;
    int swz = (bid & 7) * cpx + (bid >> 3);
    int ntn = N >> 6;
    int bm = swz / ntn, bn = swz % ntn;

    int tid = threadIdx.x;
    int lane = tid & 63, wid = tid >> 6;
    int wm = wid >> 1, wn = wid & 1;
    const int tm0 = bm * 128, tn0 = bn * 64;

    const int l8 = lane >> 3, l7 = lane & 7;
    const int bsrc = ((l7 ^ l8) << 3);   // inverse-swizzled source col (elems)

    // per-wave staging base pointers (row addresses are wave-invariant in seg)
    auto stage = [&](u16* as, u16* bs, int k0) {
#pragma unroll
        for (int i = 0; i < 4; ++i) {
            int seg = wid * 4 + i;
            const u16* g = A + (size_t)(tm0 + seg * 8 + l8) * K + k0 + bsrc;
            __builtin_amdgcn_global_load_lds(
                (const __attribute__((address_space(1))) u32*)g,
                (__attribute__((address_space(3))) u32*)(as + seg * 512), 16, 0, 0);
        }
#pragma unroll
        for (int i = 0; i < 2; ++i) {
            int seg = wid * 2 + i;
            const u16* g = Bt + (size_t)(tn0 + seg * 8 + l8) * K + k0 + bsrc;
            __builtin_amdgcn_global_load_lds(
                (const __attribute__((address_space(1))) u32*)g,
                (__attribute__((address_space(3))) u32*)(bs + seg * 512), 16, 0, 0);
        }
    };

    f32x4 acc[4][2] = {};

    int kt = K >> 6;
    stage(As[0], Bs[0], 0);
    __syncthreads();                  // vmcnt(0): buf0 ready

    int cur = 0;
    for (int t = 0; t < kt; ++t) {
        if (t + 1 < kt) stage(As[cur ^ 1], Bs[cur ^ 1], (t + 1) << 6);

        const u16* as = As[cur];
        const u16* bs = Bs[cur];
#pragma unroll
        for (int kk = 0; kk < 2; ++kk) {
            int cb = (kk << 6) + ((lane >> 4) << 4);
            bf16x8 a[4], b[2];
#pragma unroll
            for (int m = 0; m < 4; ++m) {
                int r = wm * 64 + m * 16 + (lane & 15);
                a[m] = *(const bf16x8*)((const char*)as + r * 128 + (cb ^ ((r & 7) << 4)));
            }
#pragma unroll
            for (int n = 0; n < 2; ++n) {
                int r = wn * 32 + n * 16 + (lane & 15);
                b[n] = *(const bf16x8*)((const char*)bs + r * 128 + (cb ^ ((r & 7) << 4)));
            }
#pragma unroll
            for (int m = 0; m < 4; ++m)
#pragma unroll
                for (int n = 0; n < 2; ++n)
                    acc[m][n] = __builtin_amdgcn_mfma_f32_16x16x32_bf16(
                        a[m], b[n], acc[m][n], 0, 0, 0);
        }
        __syncthreads();              // drains vmcnt (next buf ready) + lgkm (reads done)
        cur ^= 1;
    }

    // epilogue: bias + relu + bf16 store. C/D layout: col=lane&15, row=(lane>>4)*4+r
    int cr = lane >> 4, cc = lane & 15;
#pragma unroll
    for (int n = 0; n < 2; ++n) {
        int col = tn0 + wn * 32 + n * 16 + cc;
        float bv = bias[col];
#pragma unroll
        for (int m = 0; m < 4; ++m) {
            int row0 = tm0 + wm * 64 + m * 16 + cr * 4;
#pragma unroll
            for (int r = 0; r < 4; ++r) {
                float v = fmaxf(acc[m][n][r] + bv, 0.0f);
                C[(size_t)(row0 + r) * N + col] = f2bf(v);
            }
        }
    }
}

// ---------------------------------------------------------------------------
// Heads: one wave per row; 16 outputs (11 cls + 5 reg) + box decode
// ---------------------------------------------------------------------------
__global__ __launch_bounds__(256) void k_head(
    const u16* __restrict__ h2, const float* __restrict__ Whead,
    const float* __restrict__ bc, const float* __restrict__ br,
    const float* __restrict__ boxes, const float* __restrict__ strides,
    float* __restrict__ cls_out, float* __restrict__ dec_out,
    float* __restrict__ rois_out) {
    int lane = threadIdx.x & 63;
    int row = blockIdx.x * 4 + (threadIdx.x >> 6);

    const u16* hr = h2 + (size_t)row * 1024;
    float acc[16];
#pragma unroll
    for (int i = 0; i < 16; ++i) acc[i] = 0.0f;

#pragma unroll
    for (int j = 0; j < 16; ++j) {
        int k = j * 64 + lane;
        float h = bf2f(hr[k]);
        const float4* wp = (const float4*)(Whead + (size_t)k * 16);
        float4 q0 = wp[0], q1 = wp[1], q2 = wp[2], q3 = wp[3];
        acc[0]  = fmaf(h, q0.x, acc[0]);  acc[1]  = fmaf(h, q0.y, acc[1]);
        acc[2]  = fmaf(h, q0.z, acc[2]);  acc[3]  = fmaf(h, q0.w, acc[3]);
        acc[4]  = fmaf(h, q1.x, acc[4]);  acc[5]  = fmaf(h, q1.y, acc[5]);
        acc[6]  = fmaf(h, q1.z, acc[6]);  acc[7]  = fmaf(h, q1.w, acc[7]);
        acc[8]  = fmaf(h, q2.x, acc[8]);  acc[9]  = fmaf(h, q2.y, acc[9]);
        acc[10] = fmaf(h, q2.z, acc[10]); acc[11] = fmaf(h, q2.w, acc[11]);
        acc[12] = fmaf(h, q3.x, acc[12]); acc[13] = fmaf(h, q3.y, acc[13]);
        acc[14] = fmaf(h, q3.z, acc[14]); acc[15] = fmaf(h, q3.w, acc[15]);
    }
#pragma unroll
    for (int i = 0; i < 16; ++i) {
#pragma unroll
        for (int off = 32; off > 0; off >>= 1)
            acc[i] += __shfl_xor(acc[i], off);
    }

    if (lane == 0) {
        float* co = cls_out + (size_t)row * 11;
#pragma unroll
        for (int c = 0; c < 11; ++c) co[c] = acc[c] + bc[c];

        const float STD[5] = {0.1f, 0.1f, 0.2f, 0.2f, 0.1f};
        float reg[5];
#pragma unroll
        for (int j = 0; j < 5; ++j) reg[j] = (acc[11 + j] + br[j]) * STD[j];

        const float* bx = boxes + (size_t)row * 5;
        const float* st = strides + (size_t)row * 5;
        float b0 = bx[0], b1 = bx[1], b2 = bx[2], b3 = bx[3], b4 = bx[4];
        float s0 = st[0], s1 = st[1], s2 = st[2], s3 = st[3];

        float dx = b2 * reg[0] + b0;
        float dy = b3 * reg[1] + b1;
        float dw = b2 * expf(reg[2]);
        float dh = b3 * expf(reg[3]);
        float da = b4 * expf(reg[4]);

        float* dd = dec_out + (size_t)row * 5;
        dd[0] = dx * s0; dd[1] = dy * s1; dd[2] = dw * s2; dd[3] = dh * s3; dd[4] = da;

        float* rr = rois_out + (size_t)row * 5;
        rr[0] = b0 * s0; rr[1] = b1 * s1; rr[2] = b2 * s2; rr[3] = b3 * s3; rr[4] = b4;
    }
}

// ---------------------------------------------------------------------------
// launch
// ---------------------------------------------------------------------------
extern "C" void kernel_launch(void* const* d_in, const int* in_sizes, int n_in,
                              void* d_out, int out_size, void* d_ws, size_t ws_size,
                              hipStream_t stream) {
    const float* features = (const float*)d_in[0];
    const float* boxes    = (const float*)d_in[1];
    const float* strides  = (const float*)d_in[2];
    const float* W1 = (const float*)d_in[3];
    const float* b1 = (const float*)d_in[4];
    const float* W2 = (const float*)d_in[5];
    const float* b2 = (const float*)d_in[6];
    const float* Wc = (const float*)d_in[7];
    const float* bc = (const float*)d_in[8];
    const float* Wr = (const float*)d_in[9];
    const float* br = (const float*)d_in[10];

    const int M = 4096;      // B*N
    const int K = 12544;     // 256*7*7
    const int H = 1024;

    // workspace layout (bytes)
    char* ws = (char*)d_ws;
    u16*   Abf   = (u16*)(ws + 0);            // 4096*12544 bf16 = 102,760,448 B
    u16*   W1T   = (u16*)(ws + 102760448);    //  25,690,112 B
    u16*   W2T   = (u16*)(ws + 128450560);    //   2,097,152 B
    float* Whead = (float*)(ws + 130547712);  //      65,536 B
    u16*   h1    = (u16*)(ws + 130613248);    //   8,388,608 B
    u16*   h2    = (u16*)(ws + 139001856);    //   8,388,608 B
    // total 147,390,464 B

    // pack
    k_cvt_bf16<<<25088, 256, 0, stream>>>(features, Abf, 6422528);
    k_transpose_cvt<<<(K / 32) * (H / 32), 256, 0, stream>>>(W1, W1T, K, H);
    k_transpose_cvt<<<(H / 32) * (H / 32), 256, 0, stream>>>(W2, W2T, H, H);
    k_pack_head<<<4, 256, 0, stream>>>(Wc, Wr, Whead);

    // GEMM1: h1 = relu(Abf @ W1T^T + b1)   [4096 x 1024], K=12544
    k_gemm_bias_relu<<<(M / 128) * (H / 64), 256, 0, stream>>>(Abf, W1T, b1, h1, M, H, K);
    // GEMM2: h2 = relu(h1 @ W2T^T + b2)    [4096 x 1024], K=1024
    k_gemm_bias_relu<<<(M / 128) * (H / 64), 256, 0, stream>>>(h1, W2T, b2, h2, M, H, H);

    // heads + decode
    float* cls  = (float*)d_out;               // 4096*11
    float* dec  = cls + (size_t)4096 * 11;     // 4096*5
    float* rois = dec + (size_t)4096 * 5;      // 4096*5
    k_head<<<1024, 256, 0, stream>>>(h2, Whead, bc, br, boxes, strides, cls, dec, rois);
}

// Round 4
// 587.025 us; speedup vs baseline: 1.0702x; 1.0148x over previous
//
#include <hip/hip_runtime.h>
#include <hip/hip_bf16.h>
#include <stdint.h>

typedef unsigned short u16;
typedef unsigned int u32;
typedef float f32x4 __attribute__((ext_vector_type(4)));
typedef short bf16x8 __attribute__((ext_vector_type(8)));

#define DEV static __device__ __forceinline__

DEV u16 f2bf(float x) {
    u32 u = __float_as_uint(x);
    u32 r = (u + 0x7fffu + ((u >> 16) & 1u)) >> 16;   // RNE
    return (u16)r;
}
DEV float bf2f(u16 u) { return __uint_as_float(((u32)u) << 16); }
DEV u32 pk2bf(float lo, float hi) {
    u32 r;
    asm("v_cvt_pk_bf16_f32 %0, %1, %2" : "=v"(r) : "v"(lo), "v"(hi));
    return r;
}

// ---------------------------------------------------------------------------
// Pack kernels
// ---------------------------------------------------------------------------

// in [K][N] fp32 -> out [N][K] bf16 ; 32x32 LDS-tiled transpose
__global__ __launch_bounds__(256) void k_transpose_cvt(const float* __restrict__ in,
                                                       u16* __restrict__ out,
                                                       int K, int N) {
    __shared__ float tile[32][33];
    int tiles_n = N >> 5;
    int tk = blockIdx.x / tiles_n, tn = blockIdx.x % tiles_n;
    int tx = threadIdx.x & 31, ty = threadIdx.x >> 5;
    int k0 = tk * 32, n0 = tn * 32;
#pragma unroll
    for (int i = 0; i < 4; ++i)
        tile[ty * 4 + i][tx] = in[(size_t)(k0 + ty * 4 + i) * N + n0 + tx];
    __syncthreads();
#pragma unroll
    for (int i = 0; i < 4; ++i)
        out[(size_t)(n0 + ty * 4 + i) * K + k0 + tx] = f2bf(tile[tx][ty * 4 + i]);
}

// Wc [1024][11] + Wr [1024][5] -> Whead [1024][16] fp32
__global__ __launch_bounds__(256) void k_pack_head(const float* __restrict__ Wc,
                                                   const float* __restrict__ Wr,
                                                   float* __restrict__ Whead) {
    int r = blockIdx.x * 256 + threadIdx.x;
    if (r >= 1024) return;
    float* o = Whead + (size_t)r * 16;
#pragma unroll
    for (int c = 0; c < 11; ++c) o[c] = Wc[(size_t)r * 11 + c];
#pragma unroll
    for (int c = 0; c < 5; ++c) o[11 + c] = Wr[(size_t)r * 5 + c];
}

// ---------------------------------------------------------------------------
// GEMM1 (split-K=4, fused fp32->bf16 A-conversion):
//   P[split] = A_fp32[tile] @ Bt^T   (fp32 partials)
// BM=128 BN=64 BK=64, 256 thr (2x2 waves), 16x16x32 MFMA, dbuf LDS.
// A: reg-staged async split (issue fp32 loads before MFMA, cvt+ds_write after).
// B: global_load_lds with inverse-swizzled source. T2 XOR swizzle on both.
// ---------------------------------------------------------------------------
__global__ __launch_bounds__(256, 3) void k_gemm1(
    const float* __restrict__ A, const u16* __restrict__ Bt,
    float* __restrict__ P, int M, int N, int K, int KS) {
    __shared__ u16 As[2][128 * 64];   // 2 x 16 KiB
    __shared__ u16 Bs[2][64 * 64];    // 2 x  8 KiB

    int nwg = gridDim.x;              // 2048
    int cpx = nwg >> 3;
    int bid = blockIdx.x;
    int swz = (bid & 7) * cpx + (bid >> 3);   // chunked: each XCD owns contiguous swz
    int split = swz >> 9;             // 0..3
    int rest = swz & 511;
    int bm = rest >> 4, bn = rest & 15;

    int tid = threadIdx.x;
    int lane = tid & 63, wid = tid >> 6;
    int wm = wid >> 1, wn = wid & 1;
    const int tm0 = bm * 128, tn0 = bn * 64;
    const int kbeg = split * KS;

    const int l8 = lane >> 3, l7 = lane & 7;
    const int bsrc = ((l7 ^ l8) << 3);   // inverse-swizzled source col (elems)

    // ---- A: per-thread 4 slots (row, colgroup); 8 float4 in regs
    int s0r[4], s0c[4];
#pragma unroll
    for (int i = 0; i < 4; ++i) {
        int s = i * 256 + tid;
        s0r[i] = s >> 3;          // row 0..127
        s0c[i] = s & 7;           // col-group 0..7 (8 floats each)
    }

    auto loadA = [&](int k0, float4* fa) {
#pragma unroll
        for (int i = 0; i < 4; ++i) {
            const float* g = A + (size_t)(tm0 + s0r[i]) * K + k0 + s0c[i] * 8;
            fa[2 * i]     = *(const float4*)g;
            fa[2 * i + 1] = *(const float4*)(g + 4);
        }
    };
    auto writeA = [&](u16* as, const float4* fa) {
#pragma unroll
        for (int i = 0; i < 4; ++i) {
            u32 pk[4];
            pk[0] = pk2bf(fa[2 * i].x,     fa[2 * i].y);
            pk[1] = pk2bf(fa[2 * i].z,     fa[2 * i].w);
            pk[2] = pk2bf(fa[2 * i + 1].x, fa[2 * i + 1].y);
            pk[3] = pk2bf(fa[2 * i + 1].z, fa[2 * i + 1].w);
            int r = s0r[i];
            *(uint4*)((char*)as + r * 128 + ((s0c[i] << 4) ^ ((r & 7) << 4))) =
                *(const uint4*)pk;
        }
    };
    auto stageB = [&](u16* bs, int k0) {
#pragma unroll
        for (int i = 0; i < 2; ++i) {
            int seg = wid * 2 + i;
            const u16* g = Bt + (size_t)(tn0 + seg * 8 + l8) * K + k0 + bsrc;
            __builtin_amdgcn_global_load_lds(
                (const __attribute__((address_space(1))) u32*)g,
                (__attribute__((address_space(3))) u32*)(bs + seg * 512), 16, 0, 0);
        }
    };

    f32x4 acc[4][2] = {};
    float4 fa[8];

    int kt = KS >> 6;                 // 49
    // prologue: fill buf0
    loadA(kbeg, fa);
    stageB(Bs[0], kbeg);
    writeA(As[0], fa);
    __syncthreads();

    int cur = 0;
    for (int t = 0; t < kt; ++t) {
        int k1 = kbeg + ((t + 1) << 6);
        if (t + 1 < kt) {
            loadA(k1, fa);            // issue fp32 loads (consumed after MFMA)
            stageB(Bs[cur ^ 1], k1);  // async B -> next LDS buf
        }

        const u16* as = As[cur];
        const u16* bs = Bs[cur];
#pragma unroll
        for (int kk = 0; kk < 2; ++kk) {
            int cb = (kk << 6) + ((lane >> 4) << 4);
            bf16x8 a[4], b[2];
#pragma unroll
            for (int m = 0; m < 4; ++m) {
                int r = wm * 64 + m * 16 + (lane & 15);
                a[m] = *(const bf16x8*)((const char*)as + r * 128 + (cb ^ ((r & 7) << 4)));
            }
#pragma unroll
            for (int n = 0; n < 2; ++n) {
                int r = wn * 32 + n * 16 + (lane & 15);
                b[n] = *(const bf16x8*)((const char*)bs + r * 128 + (cb ^ ((r & 7) << 4)));
            }
#pragma unroll
            for (int m = 0; m < 4; ++m)
#pragma unroll
                for (int n = 0; n < 2; ++n)
                    acc[m][n] = __builtin_amdgcn_mfma_f32_16x16x32_bf16(
                        a[m], b[n], acc[m][n], 0, 0, 0);
        }

        if (t + 1 < kt) writeA(As[cur ^ 1], fa);   // waits fa, cvt, swizzled write
        __syncthreads();
        cur ^= 1;
    }

    // epilogue: fp32 partial store
    float* Ps = P + (size_t)split * M * N;
    int cr = lane >> 4, cc = lane & 15;
#pragma unroll
    for (int n = 0; n < 2; ++n) {
        int col = tn0 + wn * 32 + n * 16 + cc;
#pragma unroll
        for (int m = 0; m < 4; ++m) {
            int row0 = tm0 + wm * 64 + m * 16 + cr * 4;
#pragma unroll
            for (int r = 0; r < 4; ++r)
                Ps[(size_t)(row0 + r) * N + col] = acc[m][n][r];
        }
    }
}

// combine: h1 = bf16(relu(P0+P1+P2+P3 + bias)), 8 elems/thread
__global__ __launch_bounds__(256) void k_combine(const float* __restrict__ P,
                                                 const float* __restrict__ bias,
                                                 u16* __restrict__ out,
                                                 int MN, int N) {
    int i = blockIdx.x * 256 + threadIdx.x;
    int ncol8 = N >> 3;
    int row = i / ncol8, c8 = i - row * ncol8;
    size_t off = (size_t)row * N + (size_t)c8 * 8;
    float v[8];
    {
        const float4* p = (const float4*)(P + off);
        float4 a = p[0], b = p[1];
        v[0] = a.x; v[1] = a.y; v[2] = a.z; v[3] = a.w;
        v[4] = b.x; v[5] = b.y; v[6] = b.z; v[7] = b.w;
    }
#pragma unroll
    for (int s = 1; s < 4; ++s) {
        const float4* p = (const float4*)(P + (size_t)s * MN + off);
        float4 a = p[0], b = p[1];
        v[0] += a.x; v[1] += a.y; v[2] += a.z; v[3] += a.w;
        v[4] += b.x; v[5] += b.y; v[6] += b.z; v[7] += b.w;
    }
    const float4* bp = (const float4*)(bias + (size_t)c8 * 8);
    float4 q0 = bp[0], q1 = bp[1];
    float w0 = fmaxf(v[0] + q0.x, 0.f), w1 = fmaxf(v[1] + q0.y, 0.f);
    float w2 = fmaxf(v[2] + q0.z, 0.f), w3 = fmaxf(v[3] + q0.w, 0.f);
    float w4 = fmaxf(v[4] + q1.x, 0.f), w5 = fmaxf(v[5] + q1.y, 0.f);
    float w6 = fmaxf(v[6] + q1.z, 0.f), w7 = fmaxf(v[7] + q1.w, 0.f);
    u32 pk[4] = {pk2bf(w0, w1), pk2bf(w2, w3), pk2bf(w4, w5), pk2bf(w6, w7)};
    *(uint4*)(out + off) = *(const uint4*)pk;
}

// ---------------------------------------------------------------------------
// GEMM2: C = relu(A @ Bt^T + bias) bf16; all-bf16, gload_lds dbuf, T2 swizzle.
// ---------------------------------------------------------------------------
__global__ __launch_bounds__(256, 3) void k_gemm2(
    const u16* __restrict__ A, const u16* __restrict__ Bt,
    const float* __restrict__ bias, u16* __restrict__ C,
    int M, int N, int K) {
    __shared__ u16 As[2][128 * 64];
    __shared__ u16 Bs[2][64 * 64];

    int nwg = gridDim.x;              // 512
    int cpx = nwg >> 3;
    int bid = blockIdx.x;
    int swz = (bid & 7) * cpx + (bid >> 3);
    int ntn = N >> 6;
    int bm = swz / ntn, bn = swz % ntn;

    int tid = threadIdx.x;
    int lane = tid & 63, wid = tid >> 6;
    int wm = wid >> 1, wn = wid & 1;
    const int tm0 = bm * 128, tn0 = bn * 64;

    const int l8 = lane >> 3, l7 = lane & 7;
    const int bsrc = ((l7 ^ l8) << 3);

    auto stage = [&](u16* as, u16* bs, int k0) {
#pragma unroll
        for (int i = 0; i < 4; ++i) {
            int seg = wid * 4 + i;
            const u16* g = A + (size_t)(tm0 + seg * 8 + l8) * K + k0 + bsrc;
            __builtin_amdgcn_global_load_lds(
                (const __attribute__((address_space(1))) u32*)g,
                (__attribute__((address_space(3))) u32*)(as + seg * 512), 16, 0, 0);
        }
#pragma unroll
        for (int i = 0; i < 2; ++i) {
            int seg = wid * 2 + i;
            const u16* g = Bt + (size_t)(tn0 + seg * 8 + l8) * K + k0 + bsrc;
            __builtin_amdgcn_global_load_lds(
                (const __attribute__((address_space(1))) u32*)g,
                (__attribute__((address_space(3))) u32*)(bs + seg * 512), 16, 0, 0);
        }
    };

    f32x4 acc[4][2] = {};

    int kt = K >> 6;
    stage(As[0], Bs[0], 0);
    __syncthreads();

    int cur = 0;
    for (int t = 0; t < kt; ++t) {
        if (t + 1 < kt) stage(As[cur ^ 1], Bs[cur ^ 1], (t + 1) << 6);

        const u16* as = As[cur];
        const u16* bs = Bs[cur];
#pragma unroll
        for (int kk = 0; kk < 2; ++kk) {
            int cb = (kk << 6) + ((lane >> 4) << 4);
            bf16x8 a[4], b[2];
#pragma unroll
            for (int m = 0; m < 4; ++m) {
                int r = wm * 64 + m * 16 + (lane & 15);
                a[m] = *(const bf16x8*)((const char*)as + r * 128 + (cb ^ ((r & 7) << 4)));
            }
#pragma unroll
            for (int n = 0; n < 2; ++n) {
                int r = wn * 32 + n * 16 + (lane & 15);
                b[n] = *(const bf16x8*)((const char*)bs + r * 128 + (cb ^ ((r & 7) << 4)));
            }
#pragma unroll
            for (int m = 0; m < 4; ++m)
#pragma unroll
                for (int n = 0; n < 2; ++n)
                    acc[m][n] = __builtin_amdgcn_mfma_f32_16x16x32_bf16(
                        a[m], b[n], acc[m][n], 0, 0, 0);
        }
        __syncthreads();
        cur ^= 1;
    }

    int cr = lane >> 4, cc = lane & 15;
#pragma unroll
    for (int n = 0; n < 2; ++n) {
        int col = tn0 + wn * 32 + n * 16 + cc;
        float bv = bias[col];
#pragma unroll
        for (int m = 0; m < 4; ++m) {
            int row0 = tm0 + wm * 64 + m * 16 + cr * 4;
#pragma unroll
            for (int r = 0; r < 4; ++r) {
                float v = fmaxf(acc[m][n][r] + bv, 0.0f);
                C[(size_t)(row0 + r) * N + col] = f2bf(v);
            }
        }
    }
}

// ---------------------------------------------------------------------------
// Heads: one wave per row; 16 outputs (11 cls + 5 reg) + box decode
// ---------------------------------------------------------------------------
__global__ __launch_bounds__(256) void k_head(
    const u16* __restrict__ h2, const float* __restrict__ Whead,
    const float* __restrict__ bc, const float* __restrict__ br,
    const float* __restrict__ boxes, const float* __restrict__ strides,
    float* __restrict__ cls_out, float* __restrict__ dec_out,
    float* __restrict__ rois_out) {
    int lane = threadIdx.x & 63;
    int row = blockIdx.x * 4 + (threadIdx.x >> 6);

    const u16* hr = h2 + (size_t)row * 1024;
    float acc[16];
#pragma unroll
    for (int i = 0; i < 16; ++i) acc[i] = 0.0f;

#pragma unroll
    for (int j = 0; j < 16; ++j) {
        int k = j * 64 + lane;
        float h = bf2f(hr[k]);
        const float4* wp = (const float4*)(Whead + (size_t)k * 16);
        float4 q0 = wp[0], q1 = wp[1], q2 = wp[2], q3 = wp[3];
        acc[0]  = fmaf(h, q0.x, acc[0]);  acc[1]  = fmaf(h, q0.y, acc[1]);
        acc[2]  = fmaf(h, q0.z, acc[2]);  acc[3]  = fmaf(h, q0.w, acc[3]);
        acc[4]  = fmaf(h, q1.x, acc[4]);  acc[5]  = fmaf(h, q1.y, acc[5]);
        acc[6]  = fmaf(h, q1.z, acc[6]);  acc[7]  = fmaf(h, q1.w, acc[7]);
        acc[8]  = fmaf(h, q2.x, acc[8]);  acc[9]  = fmaf(h, q2.y, acc[9]);
        acc[10] = fmaf(h, q2.z, acc[10]); acc[11] = fmaf(h, q2.w, acc[11]);
        acc[12] = fmaf(h, q3.x, acc[12]); acc[13] = fmaf(h, q3.y, acc[13]);
        acc[14] = fmaf(h, q3.z, acc[14]); acc[15] = fmaf(h, q3.w, acc[15]);
    }
#pragma unroll
    for (int i = 0; i < 16; ++i) {
#pragma unroll
        for (int off = 32; off > 0; off >>= 1)
            acc[i] += __shfl_xor(acc[i], off);
    }

    if (lane == 0) {
        float* co = cls_out + (size_t)row * 11;
#pragma unroll
        for (int c = 0; c < 11; ++c) co[c] = acc[c] + bc[c];

        const float STD[5] = {0.1f, 0.1f, 0.2f, 0.2f, 0.1f};
        float reg[5];
#pragma unroll
        for (int j = 0; j < 5; ++j) reg[j] = (acc[11 + j] + br[j]) * STD[j];

        const float* bx = boxes + (size_t)row * 5;
        const float* st = strides + (size_t)row * 5;
        float b0 = bx[0], b1 = bx[1], b2 = bx[2], b3 = bx[3], b4 = bx[4];
        float s0 = st[0], s1 = st[1], s2 = st[2], s3 = st[3];

        float dx = b2 * reg[0] + b0;
        float dy = b3 * reg[1] + b1;
        float dw = b2 * expf(reg[2]);
        float dh = b3 * expf(reg[3]);
        float da = b4 * expf(reg[4]);

        float* dd = dec_out + (size_t)row * 5;
        dd[0] = dx * s0; dd[1] = dy * s1; dd[2] = dw * s2; dd[3] = dh * s3; dd[4] = da;

        float* rr = rois_out + (size_t)row * 5;
        rr[0] = b0 * s0; rr[1] = b1 * s1; rr[2] = b2 * s2; rr[3] = b3 * s3; rr[4] = b4;
    }
}

// ---------------------------------------------------------------------------
// launch
// ---------------------------------------------------------------------------
extern "C" void kernel_launch(void* const* d_in, const int* in_sizes, int n_in,
                              void* d_out, int out_size, void* d_ws, size_t ws_size,
                              hipStream_t stream) {
    const float* features = (const float*)d_in[0];
    const float* boxes    = (const float*)d_in[1];
    const float* strides  = (const float*)d_in[2];
    const float* W1 = (const float*)d_in[3];
    const float* b1 = (const float*)d_in[4];
    const float* W2 = (const float*)d_in[5];
    const float* b2 = (const float*)d_in[6];
    const float* Wc = (const float*)d_in[7];
    const float* bc = (const float*)d_in[8];
    const float* Wr = (const float*)d_in[9];
    const float* br = (const float*)d_in[10];

    const int M = 4096;      // B*N
    const int K = 12544;     // 256*7*7
    const int H = 1024;

    // workspace layout (bytes)
    char* ws = (char*)d_ws;
    u16*   W1T   = (u16*)(ws + 0);            // 25,690,112 B
    u16*   W2T   = (u16*)(ws + 25690112);     //  2,097,152 B
    float* Whead = (float*)(ws + 27787264);   //     65,536 B
    float* P     = (float*)(ws + 27852800);   // 67,108,864 B (4 x 16 MB fp32)
    u16*   h1    = (u16*)(ws + 94961664);     //  8,388,608 B
    u16*   h2    = (u16*)(ws + 103350272);    //  8,388,608 B
    // total 111,738,880 B

    // weights pack
    k_transpose_cvt<<<(K / 32) * (H / 32), 256, 0, stream>>>(W1, W1T, K, H);
    k_transpose_cvt<<<(H / 32) * (H / 32), 256, 0, stream>>>(W2, W2T, H, H);
    k_pack_head<<<4, 256, 0, stream>>>(Wc, Wr, Whead);

    // GEMM1 split-K=4, fused A conversion: P[s] = features @ W1T^T
    k_gemm1<<<2048, 256, 0, stream>>>(features, W1T, P, M, H, K, K / 4);
    // h1 = relu(sum P + b1) in bf16
    k_combine<<<(M * H / 8) / 256, 256, 0, stream>>>(P, b1, h1, M * H, H);
    // GEMM2: h2 = relu(h1 @ W2T^T + b2)
    k_gemm2<<<(M / 128) * (H / 64), 256, 0, stream>>>(h1, W2T, b2, h2, M, H, H);

    // heads + decode
    float* cls  = (float*)d_out;               // 4096*11
    float* dec  = cls + (size_t)4096 * 11;     // 4096*5
    float* rois = dec + (size_t)4096 * 5;      // 4096*5
    k_head<<<1024, 256, 0, stream>>>(h2, Whead, bc, br, boxes, strides, cls, dec, rois);
}

// Round 5
// 534.341 us; speedup vs baseline: 1.1757x; 1.0986x over previous
//
#include <hip/hip_runtime.h>
#include <hip/hip_bf16.h>
#include <stdint.h>

typedef unsigned short u16;
typedef unsigned int u32;
typedef _Float16 f16;
typedef float f32x4 __attribute__((ext_vector_type(4)));
typedef short bf16x8 __attribute__((ext_vector_type(8)));

#define DEV static __device__ __forceinline__

DEV u16 f2bf(float x) {
    u32 u = __float_as_uint(x);
    u32 r = (u + 0x7fffu + ((u >> 16) & 1u)) >> 16;   // RNE
    return (u16)r;
}
DEV float bf2f(u16 u) { return __uint_as_float(((u32)u) << 16); }
DEV u32 pk2bf(float lo, float hi) {
    u32 r;
    asm("v_cvt_pk_bf16_f32 %0, %1, %2" : "=v"(r) : "v"(lo), "v"(hi));
    return r;
}
DEV u16 f2h(float x) { f16 v = (f16)x; return *(u16*)&v; }
DEV float h2f(u16 u) { f16 v = *(f16*)&u; return (float)v; }

// ---------------------------------------------------------------------------
// Pack kernels
// ---------------------------------------------------------------------------

// fp32 -> bf16, 8 elems/thread, coalesced
__global__ __launch_bounds__(256) void k_cvt_bf16(const float* __restrict__ in,
                                                  u16* __restrict__ out, int n8) {
    int i = blockIdx.x * 256 + threadIdx.x;
    if (i >= n8) return;
    const float4* p = (const float4*)in + (size_t)i * 2;
    float4 a = p[0], b = p[1];
    u32 pk[4] = {pk2bf(a.x, a.y), pk2bf(a.z, a.w), pk2bf(b.x, b.y), pk2bf(b.z, b.w)};
    *(uint4*)(out + (size_t)i * 8) = *(const uint4*)pk;
}

// in [K][N] fp32 -> out [N][K] bf16 ; 32x32 LDS-tiled transpose
__global__ __launch_bounds__(256) void k_transpose_cvt(const float* __restrict__ in,
                                                       u16* __restrict__ out,
                                                       int K, int N) {
    __shared__ float tile[32][33];
    int tiles_n = N >> 5;
    int tk = blockIdx.x / tiles_n, tn = blockIdx.x % tiles_n;
    int tx = threadIdx.x & 31, ty = threadIdx.x >> 5;
    int k0 = tk * 32, n0 = tn * 32;
#pragma unroll
    for (int i = 0; i < 4; ++i)
        tile[ty * 4 + i][tx] = in[(size_t)(k0 + ty * 4 + i) * N + n0 + tx];
    __syncthreads();
#pragma unroll
    for (int i = 0; i < 4; ++i)
        out[(size_t)(n0 + ty * 4 + i) * K + k0 + tx] = f2bf(tile[tx][ty * 4 + i]);
}

// ---------------------------------------------------------------------------
// GEMM1 (split-K=2): Ph[split] = fp16( A @ Bt^T ) partials.
// m97 structure: BM=BN=128 BK=64, single-buffered LDS (32 KiB), 4 waves 2x2,
// each wave 64x64 out (acc[4][4]), 16x16x32 MFMA, 2 barriers per K-step.
// A,B both bf16 via global_load_lds; T2 XOR swizzle (inverse-swizzled source).
// ---------------------------------------------------------------------------
__global__ __launch_bounds__(256) void k_gemm1(
    const u16* __restrict__ A, const u16* __restrict__ Bt,
    u16* __restrict__ P, int M, int N, int K, int KS) {
    __shared__ u16 As[128 * 64];   // 16 KiB
    __shared__ u16 Bs[128 * 64];   // 16 KiB

    int nwg = gridDim.x;              // 512
    int cpx = nwg >> 3;               // 64
    int bid = blockIdx.x;
    int swz = (bid & 7) * cpx + (bid >> 3);   // chunked XCD swizzle
    int split = swz >> 8;             // 0..1
    int rest = swz & 255;
    int bm = rest >> 3, bn = rest & 7;   // bm-major: 8 consecutive share A-panel

    int tid = threadIdx.x;
    int lane = tid & 63, wid = tid >> 6;
    int wm = wid >> 1, wn = wid & 1;
    const int tm0 = bm * 128, tn0 = bn * 128;
    const int kbeg = split * KS;

    const int l8 = lane >> 3, l7 = lane & 7;
    const int bsrc = ((l7 ^ l8) << 3);   // inverse-swizzled source col (elems)

    f32x4 acc[4][4] = {};

    int kt = KS >> 6;                 // 98
    for (int t = 0; t < kt; ++t) {
        int k0 = kbeg + (t << 6);
        // stage A: 16 segs (8 rows x 1 KiB each), wave owns 4
#pragma unroll
        for (int i = 0; i < 4; ++i) {
            int seg = wid * 4 + i;
            const u16* g = A + (size_t)(tm0 + seg * 8 + l8) * K + k0 + bsrc;
            __builtin_amdgcn_global_load_lds(
                (const __attribute__((address_space(1))) u32*)g,
                (__attribute__((address_space(3))) u32*)&As[seg * 512], 16, 0, 0);
        }
        // stage B: 16 segs
#pragma unroll
        for (int i = 0; i < 4; ++i) {
            int seg = wid * 4 + i;
            const u16* g = Bt + (size_t)(tn0 + seg * 8 + l8) * K + k0 + bsrc;
            __builtin_amdgcn_global_load_lds(
                (const __attribute__((address_space(1))) u32*)g,
                (__attribute__((address_space(3))) u32*)&Bs[seg * 512], 16, 0, 0);
        }
        __syncthreads();   // vmcnt(0): tiles ready

#pragma unroll
        for (int kk = 0; kk < 2; ++kk) {
            int cb = (kk << 6) + ((lane >> 4) << 4);
            bf16x8 a[4], b[4];
#pragma unroll
            for (int m = 0; m < 4; ++m) {
                int r = wm * 64 + m * 16 + (lane & 15);
                a[m] = *(const bf16x8*)((const char*)As + r * 128 + (cb ^ ((r & 7) << 4)));
            }
#pragma unroll
            for (int n = 0; n < 4; ++n) {
                int r = wn * 64 + n * 16 + (lane & 15);
                b[n] = *(const bf16x8*)((const char*)Bs + r * 128 + (cb ^ ((r & 7) << 4)));
            }
#pragma unroll
            for (int m = 0; m < 4; ++m)
#pragma unroll
                for (int n = 0; n < 4; ++n)
                    acc[m][n] = __builtin_amdgcn_mfma_f32_16x16x32_bf16(
                        a[m], b[n], acc[m][n], 0, 0, 0);
        }
        __syncthreads();
    }

    // epilogue: fp16 partial store
    u16* Ps = P + (size_t)split * M * N;
    int cr = lane >> 4, cc = lane & 15;
#pragma unroll
    for (int n = 0; n < 4; ++n) {
        int col = tn0 + wn * 64 + n * 16 + cc;
#pragma unroll
        for (int m = 0; m < 4; ++m) {
            int row0 = tm0 + wm * 64 + m * 16 + cr * 4;
#pragma unroll
            for (int r = 0; r < 4; ++r)
                Ps[(size_t)(row0 + r) * N + col] = f2h(acc[m][n][r]);
        }
    }
}

// combine: h1 = bf16(relu(P0 + P1 + bias)), fp16 partials, 8 elems/thread.
// NOTE: h1 aliases P0 (each thread writes exactly the slot it read) — safe.
__global__ __launch_bounds__(256) void k_combine(const u16* __restrict__ P,
                                                 const float* __restrict__ bias,
                                                 u16* __restrict__ out,
                                                 int MN, int N) {
    int i = blockIdx.x * 256 + threadIdx.x;
    int ncol8 = N >> 3;
    int row = i / ncol8, c8 = i - row * ncol8;
    size_t off = (size_t)row * N + (size_t)c8 * 8;
    uint4 r0 = *(const uint4*)(P + off);
    uint4 r1 = *(const uint4*)(P + (size_t)MN + off);
    const u16* a = (const u16*)&r0;
    const u16* b = (const u16*)&r1;
    const float4* bp = (const float4*)(bias + (size_t)c8 * 8);
    float4 q0 = bp[0], q1 = bp[1];
    float v[8];
#pragma unroll
    for (int j = 0; j < 8; ++j) v[j] = h2f(a[j]) + h2f(b[j]);
    v[0] = fmaxf(v[0] + q0.x, 0.f); v[1] = fmaxf(v[1] + q0.y, 0.f);
    v[2] = fmaxf(v[2] + q0.z, 0.f); v[3] = fmaxf(v[3] + q0.w, 0.f);
    v[4] = fmaxf(v[4] + q1.x, 0.f); v[5] = fmaxf(v[5] + q1.y, 0.f);
    v[6] = fmaxf(v[6] + q1.z, 0.f); v[7] = fmaxf(v[7] + q1.w, 0.f);
    u32 pk[4] = {pk2bf(v[0], v[1]), pk2bf(v[2], v[3]), pk2bf(v[4], v[5]), pk2bf(v[6], v[7])};
    *(uint4*)(out + off) = *(const uint4*)pk;
}

// ---------------------------------------------------------------------------
// GEMM2: C = relu(A @ Bt^T + bias) bf16. Same m97 structure, BM=BN=128.
// ---------------------------------------------------------------------------
__global__ __launch_bounds__(256) void k_gemm2(
    const u16* __restrict__ A, const u16* __restrict__ Bt,
    const float* __restrict__ bias, u16* __restrict__ C,
    int M, int N, int K) {
    __shared__ u16 As[128 * 64];
    __shared__ u16 Bs[128 * 64];

    int nwg = gridDim.x;              // 256
    int cpx = nwg >> 3;
    int bid = blockIdx.x;
    int swz = (bid & 7) * cpx + (bid >> 3);
    int ntn = N >> 7;                 // 8
    int bm = swz / ntn, bn = swz % ntn;

    int tid = threadIdx.x;
    int lane = tid & 63, wid = tid >> 6;
    int wm = wid >> 1, wn = wid & 1;
    const int tm0 = bm * 128, tn0 = bn * 128;

    const int l8 = lane >> 3, l7 = lane & 7;
    const int bsrc = ((l7 ^ l8) << 3);

    f32x4 acc[4][4] = {};

    int kt = K >> 6;                  // 16
    for (int t = 0; t < kt; ++t) {
        int k0 = t << 6;
#pragma unroll
        for (int i = 0; i < 4; ++i) {
            int seg = wid * 4 + i;
            const u16* g = A + (size_t)(tm0 + seg * 8 + l8) * K + k0 + bsrc;
            __builtin_amdgcn_global_load_lds(
                (const __attribute__((address_space(1))) u32*)g,
                (__attribute__((address_space(3))) u32*)&As[seg * 512], 16, 0, 0);
        }
#pragma unroll
        for (int i = 0; i < 4; ++i) {
            int seg = wid * 4 + i;
            const u16* g = Bt + (size_t)(tn0 + seg * 8 + l8) * K + k0 + bsrc;
            __builtin_amdgcn_global_load_lds(
                (const __attribute__((address_space(1))) u32*)g,
                (__attribute__((address_space(3))) u32*)&Bs[seg * 512], 16, 0, 0);
        }
        __syncthreads();

#pragma unroll
        for (int kk = 0; kk < 2; ++kk) {
            int cb = (kk << 6) + ((lane >> 4) << 4);
            bf16x8 a[4], b[4];
#pragma unroll
            for (int m = 0; m < 4; ++m) {
                int r = wm * 64 + m * 16 + (lane & 15);
                a[m] = *(const bf16x8*)((const char*)As + r * 128 + (cb ^ ((r & 7) << 4)));
            }
#pragma unroll
            for (int n = 0; n < 4; ++n) {
                int r = wn * 64 + n * 16 + (lane & 15);
                b[n] = *(const bf16x8*)((const char*)Bs + r * 128 + (cb ^ ((r & 7) << 4)));
            }
#pragma unroll
            for (int m = 0; m < 4; ++m)
#pragma unroll
                for (int n = 0; n < 4; ++n)
                    acc[m][n] = __builtin_amdgcn_mfma_f32_16x16x32_bf16(
                        a[m], b[n], acc[m][n], 0, 0, 0);
        }
        __syncthreads();
    }

    int cr = lane >> 4, cc = lane & 15;
#pragma unroll
    for (int n = 0; n < 4; ++n) {
        int col = tn0 + wn * 64 + n * 16 + cc;
        float bv = bias[col];
#pragma unroll
        for (int m = 0; m < 4; ++m) {
            int row0 = tm0 + wm * 64 + m * 16 + cr * 4;
#pragma unroll
            for (int r = 0; r < 4; ++r) {
                float v = fmaxf(acc[m][n][r] + bv, 0.0f);
                C[(size_t)(row0 + r) * N + col] = f2bf(v);
            }
        }
    }
}

// ---------------------------------------------------------------------------
// Heads: one wave per row; 16 outputs (11 cls + 5 reg) + box decode.
// Reads Wc/Wr directly (small, L1/L2-resident).
// ---------------------------------------------------------------------------
__global__ __launch_bounds__(256) void k_head(
    const u16* __restrict__ h2, const float* __restrict__ Wc,
    const float* __restrict__ Wr,
    const float* __restrict__ bc, const float* __restrict__ br,
    const float* __restrict__ boxes, const float* __restrict__ strides,
    float* __restrict__ cls_out, float* __restrict__ dec_out,
    float* __restrict__ rois_out) {
    int lane = threadIdx.x & 63;
    int row = blockIdx.x * 4 + (threadIdx.x >> 6);

    const u16* hr = h2 + (size_t)row * 1024;
    float acc[16];
#pragma unroll
    for (int i = 0; i < 16; ++i) acc[i] = 0.0f;

#pragma unroll
    for (int j = 0; j < 16; ++j) {
        int k = j * 64 + lane;
        float h = bf2f(hr[k]);
        const float* wc = Wc + (size_t)k * 11;
        const float* wr = Wr + (size_t)k * 5;
#pragma unroll
        for (int c = 0; c < 11; ++c) acc[c] = fmaf(h, wc[c], acc[c]);
#pragma unroll
        for (int c = 0; c < 5; ++c) acc[11 + c] = fmaf(h, wr[c], acc[11 + c]);
    }
#pragma unroll
    for (int i = 0; i < 16; ++i) {
#pragma unroll
        for (int off = 32; off > 0; off >>= 1)
            acc[i] += __shfl_xor(acc[i], off);
    }

    if (lane == 0) {
        float* co = cls_out + (size_t)row * 11;
#pragma unroll
        for (int c = 0; c < 11; ++c) co[c] = acc[c] + bc[c];

        const float STD[5] = {0.1f, 0.1f, 0.2f, 0.2f, 0.1f};
        float reg[5];
#pragma unroll
        for (int j = 0; j < 5; ++j) reg[j] = (acc[11 + j] + br[j]) * STD[j];

        const float* bx = boxes + (size_t)row * 5;
        const float* st = strides + (size_t)row * 5;
        float b0 = bx[0], b1 = bx[1], b2 = bx[2], b3 = bx[3], b4 = bx[4];
        float s0 = st[0], s1 = st[1], s2 = st[2], s3 = st[3];

        float dx = b2 * reg[0] + b0;
        float dy = b3 * reg[1] + b1;
        float dw = b2 * expf(reg[2]);
        float dh = b3 * expf(reg[3]);
        float da = b4 * expf(reg[4]);

        float* dd = dec_out + (size_t)row * 5;
        dd[0] = dx * s0; dd[1] = dy * s1; dd[2] = dw * s2; dd[3] = dh * s3; dd[4] = da;

        float* rr = rois_out + (size_t)row * 5;
        rr[0] = b0 * s0; rr[1] = b1 * s1; rr[2] = b2 * s2; rr[3] = b3 * s3; rr[4] = b4;
    }
}

// ---------------------------------------------------------------------------
// launch
// ---------------------------------------------------------------------------
extern "C" void kernel_launch(void* const* d_in, const int* in_sizes, int n_in,
                              void* d_out, int out_size, void* d_ws, size_t ws_size,
                              hipStream_t stream) {
    const float* features = (const float*)d_in[0];
    const float* boxes    = (const float*)d_in[1];
    const float* strides  = (const float*)d_in[2];
    const float* W1 = (const float*)d_in[3];
    const float* b1 = (const float*)d_in[4];
    const float* W2 = (const float*)d_in[5];
    const float* b2 = (const float*)d_in[6];
    const float* Wc = (const float*)d_in[7];
    const float* bc = (const float*)d_in[8];
    const float* Wr = (const float*)d_in[9];
    const float* br = (const float*)d_in[10];

    const int M = 4096;      // B*N
    const int K = 12544;     // 256*7*7
    const int H = 1024;

    // workspace layout (bytes); proven budget 147,390,464
    char* ws = (char*)d_ws;
    u16* Abf = (u16*)(ws + 0);               // 102,760,448
    u16* W1T = (u16*)(ws + 102760448);       //  25,690,112
    u16* W2T = (u16*)(ws + 128450560);       //   2,097,152
    u16* P   = (u16*)(ws + 130547712);       //  16,777,216 (2 x fp16 MN)
    u16* h1  = P;                            // aliases P0 (safe: combine)
    u16* h2  = P + (size_t)M * H;            // aliases P1 (dead after combine)
    // end: 147,324,928

    // pack
    k_cvt_bf16<<<25088, 256, 0, stream>>>(features, Abf, 6422528);
    k_transpose_cvt<<<(K / 32) * (H / 32), 256, 0, stream>>>(W1, W1T, K, H);
    k_transpose_cvt<<<(H / 32) * (H / 32), 256, 0, stream>>>(W2, W2T, H, H);

    // GEMM1 split-K=2: P[s] = fp16(Abf @ W1T^T), 128x128 tiles
    k_gemm1<<<512, 256, 0, stream>>>(Abf, W1T, P, M, H, K, K / 2);
    // h1 = relu(P0 + P1 + b1) bf16
    k_combine<<<(M * H / 8) / 256, 256, 0, stream>>>(P, b1, h1, M * H, H);
    // GEMM2: h2 = relu(h1 @ W2T^T + b2)
    k_gemm2<<<(M / 128) * (H / 128), 256, 0, stream>>>(h1, W2T, b2, h2, M, H, H);

    // heads + decode
    float* cls  = (float*)d_out;               // 4096*11
    float* dec  = cls + (size_t)4096 * 11;     // 4096*5
    float* rois = dec + (size_t)4096 * 5;      // 4096*5
    k_head<<<1024, 256, 0, stream>>>(h2, Wc, Wr, bc, br, boxes, strides, cls, dec, rois);
}